// Round 1
// baseline (19.896 us; speedup 1.0000x reference)
//
#include <hip/hip_runtime.h>

// Problem constants (from reference setup_inputs):
// m=8, nc=64, nt=64, dx=2, dy=1, H=128, D=128
#define NC 64
#define NT 64
#define NH 128
#define ND 128

// Kernel 1: one block per (m, h). Computes hsum[m, t, h] for all t in 0..63.
//
// Separability: a[t,i]+b[i,j]+c[i]+d[j]+b1h = base_t + g_i + v_j with
//   base_t = xt_t . Wa + b1h
//   g_i    = xc_i . Wb - xc_i . Wa + yc_i * wc
//   v_j    = yc_j * wd - xc_j . Wb
// hsum[t] = sum_{i,j} relu(base_t+g_i+v_j)
//         = 0.5*sum|...| + 2048*base_t + 32*(sumG + sumV)    (relu(x)=(x+|x|)/2)
__global__ __launch_bounds__(256) void k_hsum(
    const float* __restrict__ xc,   // (m,64,2)
    const float* __restrict__ yc,   // (m,64,1)
    const float* __restrict__ xt,   // (m,64,2)
    const float* __restrict__ W1,   // (6,128)
    const float* __restrict__ b1,   // (128)
    float* __restrict__ hsum)       // (m,64,128)
{
    const int bx   = blockIdx.x;
    const int m    = bx >> 7;       // bx / 128
    const int h    = bx & 127;
    const int tid  = threadIdx.x;
    const int lane = tid & 63;      // t index
    const int w    = tid >> 6;      // wave id 0..3 (i-slice)

    const float wa0 = W1[0 * NH + h];
    const float wa1 = W1[1 * NH + h];
    const float wb0 = W1[2 * NH + h];
    const float wb1 = W1[3 * NH + h];
    const float wc  = W1[4 * NH + h];
    const float wd  = W1[5 * NH + h];
    const float b1h = b1[h];

    __shared__ float sG[NC];
    __shared__ float sV[NC];
    __shared__ float sSum[2];
    __shared__ float sAcc[4][NT];

    // Wave 0 fills g/v and reduces their sums.
    if (tid < 64) {
        const int i = tid;
        const float* xcp = xc + ((size_t)m * NC + i) * 2;
        const float x0 = xcp[0];
        const float x1 = xcp[1];
        const float yv = yc[(size_t)m * NC + i];
        const float r  = x0 * wb0 + x1 * wb1;   // xc_i . Wb
        const float a  = x0 * wa0 + x1 * wa1;   // xc_i . Wa
        const float g  = r - a + yv * wc;
        const float v  = yv * wd - r;
        sG[i] = g;
        sV[i] = v;
        float pg = g, pv = v;
        #pragma unroll
        for (int d = 32; d >= 1; d >>= 1) {
            pg += __shfl_xor(pg, d, 64);
            pv += __shfl_xor(pv, d, 64);
        }
        if (i == 0) { sSum[0] = pg; sSum[1] = pv; }
    }

    // Every thread's t-dependent base.
    const float* xtp = xt + ((size_t)m * NT + lane) * 2;
    const float base_t = xtp[0] * wa0 + xtp[1] * wa1 + b1h;

    __syncthreads();

    // Each wave handles 16 i values; all 64 lanes of a wave share i
    // (broadcast LDS reads, conflict-free), lane = t.
    float acc = 0.0f;
    #pragma unroll 1
    for (int ii = 0; ii < 16; ++ii) {
        const int i = (w << 4) + ii;
        const float u = base_t + sG[i];
        #pragma unroll
        for (int j = 0; j < NC; j += 4) {
            const float4 v4 = *(const float4*)&sV[j];
            acc += fabsf(u + v4.x);
            acc += fabsf(u + v4.y);
            acc += fabsf(u + v4.z);
            acc += fabsf(u + v4.w);
        }
    }

    sAcc[w][lane] = acc;
    __syncthreads();

    if (tid < 64) {
        const float tot = sAcc[0][lane] + sAcc[1][lane] + sAcc[2][lane] + sAcc[3][lane];
        const float res = 0.5f * tot + 2048.0f * base_t + 32.0f * (sSum[0] + sSum[1]);
        hsum[((size_t)m * NT + lane) * NH + h] = res;
    }
}

// Kernel 2: out[mt, d] = sum_h hsum[mt, h] * W2[h, d] + 4096 * b2[d]
__global__ __launch_bounds__(128) void k_out(
    const float* __restrict__ hsum,  // (m*64, 128)
    const float* __restrict__ W2,    // (128, 128)
    const float* __restrict__ b2,    // (128)
    float* __restrict__ out)         // (m*64, 128)
{
    const int mt = blockIdx.x;
    const int d  = threadIdx.x;

    __shared__ float sh[NH];
    sh[d] = hsum[(size_t)mt * NH + d];
    __syncthreads();

    float acc = 4096.0f * b2[d];
    #pragma unroll 8
    for (int hh = 0; hh < NH; ++hh) {
        acc += sh[hh] * W2[hh * ND + d];
    }
    out[(size_t)mt * ND + d] = acc;
}

extern "C" void kernel_launch(void* const* d_in, const int* in_sizes, int n_in,
                              void* d_out, int out_size, void* d_ws, size_t ws_size,
                              hipStream_t stream) {
    const float* xc = (const float*)d_in[0];
    const float* yc = (const float*)d_in[1];
    const float* xt = (const float*)d_in[2];
    const float* W1 = (const float*)d_in[3];
    const float* b1 = (const float*)d_in[4];
    const float* W2 = (const float*)d_in[5];
    const float* b2 = (const float*)d_in[6];
    float* out = (float*)d_out;

    const int m = in_sizes[0] / (NC * 2);   // 8 for the reference setup

    float* hsum = (float*)d_ws;             // m*64*128 floats = 1 MB for m=8

    k_hsum<<<m * NH, 256, 0, stream>>>(xc, yc, xt, W1, b1, hsum);
    k_out<<<m * NT, 128, 0, stream>>>(hsum, W2, b2, out);
}